// Round 1
// baseline (1193.404 us; speedup 1.0000x reference)
//
#include <hip/hip_runtime.h>
#include <hip/hip_bf16.h>
#include <math.h>

#define TT    1024   // B*S tokens
#define DD    768    // hidden dim
#define NHEAD 12
#define HDIM  64
#define NBLK  16     // T / 64
#define NMID  14     // NBLK - 2
#define NCOUT 16
#define NEGV  -1000000000.0f

// ---------------------------------------------------------------------------
// QKV projection: X[T,D] @ {Wq,Wk,Wv}[D,D] + bias, scattered to [H][T][64]
// ---------------------------------------------------------------------------
__global__ __launch_bounds__(256) void qkv_gemm_k(
    const float* __restrict__ X,
    const float* __restrict__ Wq, const float* __restrict__ bq,
    const float* __restrict__ Wk, const float* __restrict__ bk,
    const float* __restrict__ Wv, const float* __restrict__ bv,
    float* __restrict__ qo, float* __restrict__ ko, float* __restrict__ vo)
{
    const float* W; const float* bias; float* out;
    if (blockIdx.z == 0)      { W = Wq; bias = bq; out = qo; }
    else if (blockIdx.z == 1) { W = Wk; bias = bk; out = ko; }
    else                      { W = Wv; bias = bv; out = vo; }

    __shared__ float As[16][65];
    __shared__ float Bs[16][65];
    int tid = threadIdx.x;
    int tx = tid & 15, ty = tid >> 4;
    int row0 = blockIdx.x * 64;
    int head = blockIdx.y;          // col tile == head (64-wide)
    int col0 = head * 64;
    float acc[4][4] = {};

    for (int k0 = 0; k0 < DD; k0 += 16) {
        #pragma unroll
        for (int i = 0; i < 4; i++) {
            int e = tid + i * 256;
            int r = e >> 4, kk = e & 15;
            As[kk][r] = X[(row0 + r) * DD + k0 + kk];
        }
        #pragma unroll
        for (int i = 0; i < 4; i++) {
            int e = tid + i * 256;
            int kk = e >> 6, c = e & 63;
            Bs[kk][c] = W[(k0 + kk) * DD + col0 + c];
        }
        __syncthreads();
        #pragma unroll
        for (int kk = 0; kk < 16; kk++) {
            float a[4], b[4];
            #pragma unroll
            for (int i = 0; i < 4; i++) a[i] = As[kk][ty * 4 + i];
            #pragma unroll
            for (int j = 0; j < 4; j++) b[j] = Bs[kk][tx * 4 + j];
            #pragma unroll
            for (int i = 0; i < 4; i++)
                #pragma unroll
                for (int j = 0; j < 4; j++)
                    acc[i][j] += a[i] * b[j];
        }
        __syncthreads();
    }
    #pragma unroll
    for (int i = 0; i < 4; i++) {
        int r = row0 + ty * 4 + i;
        #pragma unroll
        for (int j = 0; j < 4; j++) {
            int d = tx * 4 + j;
            out[(head * TT + r) * HDIM + d] = acc[i][j] + bias[col0 + d];
        }
    }
}

// ---------------------------------------------------------------------------
// Generic GEMM: C[T,D] = A[T,D] @ W[D,D] + bias
// ---------------------------------------------------------------------------
__global__ __launch_bounds__(256) void gemm_bias_k(
    const float* __restrict__ A, const float* __restrict__ W,
    const float* __restrict__ bias, float* __restrict__ C)
{
    __shared__ float As[16][65];
    __shared__ float Bs[16][65];
    int tid = threadIdx.x;
    int tx = tid & 15, ty = tid >> 4;
    int row0 = blockIdx.x * 64;
    int col0 = blockIdx.y * 64;
    float acc[4][4] = {};

    for (int k0 = 0; k0 < DD; k0 += 16) {
        #pragma unroll
        for (int i = 0; i < 4; i++) {
            int e = tid + i * 256;
            int r = e >> 4, kk = e & 15;
            As[kk][r] = A[(row0 + r) * DD + k0 + kk];
        }
        #pragma unroll
        for (int i = 0; i < 4; i++) {
            int e = tid + i * 256;
            int kk = e >> 6, c = e & 63;
            Bs[kk][c] = W[(k0 + kk) * DD + col0 + c];
        }
        __syncthreads();
        #pragma unroll
        for (int kk = 0; kk < 16; kk++) {
            float a[4], b[4];
            #pragma unroll
            for (int i = 0; i < 4; i++) a[i] = As[kk][ty * 4 + i];
            #pragma unroll
            for (int j = 0; j < 4; j++) b[j] = Bs[kk][tx * 4 + j];
            #pragma unroll
            for (int i = 0; i < 4; i++)
                #pragma unroll
                for (int j = 0; j < 4; j++)
                    acc[i][j] += a[i] * b[j];
        }
        __syncthreads();
    }
    #pragma unroll
    for (int i = 0; i < 4; i++) {
        int r = row0 + ty * 4 + i;
        #pragma unroll
        for (int j = 0; j < 4; j++) {
            int c = col0 + tx * 4 + j;
            C[r * DD + c] = acc[i][j] + bias[c];
        }
    }
}

// ---------------------------------------------------------------------------
// Mid-block sparse attention. One 64-thread block per (mid-block n, head h).
// Gathered key blocks: [0, 15, n, n+1, n+2, rnd0, rnd1, rnd2].
// Fully-online softmax (no runtime-indexed local arrays).
// ---------------------------------------------------------------------------
__global__ __launch_bounds__(64) void attn_mid_k(
    const float* __restrict__ q, const float* __restrict__ k,
    const float* __restrict__ v, const int* __restrict__ mask,
    const int* __restrict__ rnd, float* __restrict__ ctx)
{
    int n = blockIdx.x;    // 0..13
    int h = blockIdx.y;
    int r = threadIdx.x;   // 0..63 = query row in block
    __shared__ float Ks[64][64];
    __shared__ float Vs[64][64];
    __shared__ float Ms[64];

    int qtok = (n + 1) * 64 + r;
    float qreg[64];
    const float* qrow = q + (size_t)(h * TT + qtok) * HDIM;
    #pragma unroll
    for (int d = 0; d < 64; d += 4) {
        float4 t = *(const float4*)(qrow + d);
        qreg[d] = t.x; qreg[d + 1] = t.y; qreg[d + 2] = t.z; qreg[d + 3] = t.w;
    }

    int blk[8];
    blk[0] = 0; blk[1] = NBLK - 1; blk[2] = n; blk[3] = n + 1; blk[4] = n + 2;
    blk[5] = rnd[n * 3 + 0]; blk[6] = rnd[n * 3 + 1]; blk[7] = rnd[n * 3 + 2];

    float m = -3.0e38f, l = 0.0f;
    float acc[64];
    #pragma unroll
    for (int d = 0; d < 64; d++) acc[d] = 0.0f;

    for (int b = 0; b < 8; b++) {
        int bi = blk[b];
        const float* krow = k + (size_t)(h * TT + bi * 64 + r) * HDIM;
        const float* vrow = v + (size_t)(h * TT + bi * 64 + r) * HDIM;
        #pragma unroll
        for (int d = 0; d < 64; d += 4) {
            *(float4*)(&Ks[r][d]) = *(const float4*)(krow + d);
            *(float4*)(&Vs[r][d]) = *(const float4*)(vrow + d);
        }
        Ms[r] = (float)mask[bi * 64 + r];
        __syncthreads();

        for (int j = 0; j < 64; j++) {
            float s = 0.0f;
            #pragma unroll
            for (int d = 0; d < 64; d++) s += qreg[d] * Ks[j][d];
            s *= 0.125f;
            if (Ms[j] <= 0.0f) s = NEGV;
            if (s > m) {
                float fac = __expf(m - s);
                l *= fac;
                #pragma unroll
                for (int d = 0; d < 64; d++) acc[d] *= fac;
                m = s;
            }
            float p = __expf(s - m);
            l += p;
            #pragma unroll
            for (int d = 0; d < 64; d++) acc[d] += p * Vs[j][d];
        }
        __syncthreads();
    }
    float inv = 1.0f / l;
    float* crow = ctx + (size_t)qtok * DD + h * HDIM;
    #pragma unroll
    for (int d = 0; d < 64; d++) crow[d] = acc[d] * inv;
}

// ---------------------------------------------------------------------------
// Global attention for blocks 0 and 15 (attend over all T keys).
// ---------------------------------------------------------------------------
__global__ __launch_bounds__(64) void attn_glob_k(
    const float* __restrict__ q, const float* __restrict__ k,
    const float* __restrict__ v, const int* __restrict__ mask,
    float* __restrict__ ctx)
{
    int g = blockIdx.x;    // 0,1
    int h = blockIdx.y;
    int r = threadIdx.x;
    __shared__ float Ks[64][64];
    __shared__ float Vs[64][64];
    __shared__ float Ms[64];

    int qb = g ? (NBLK - 1) : 0;
    int qtok = qb * 64 + r;
    float qreg[64];
    const float* qrow = q + (size_t)(h * TT + qtok) * HDIM;
    #pragma unroll
    for (int d = 0; d < 64; d += 4) {
        float4 t = *(const float4*)(qrow + d);
        qreg[d] = t.x; qreg[d + 1] = t.y; qreg[d + 2] = t.z; qreg[d + 3] = t.w;
    }

    float m = -3.0e38f, l = 0.0f;
    float acc[64];
    #pragma unroll
    for (int d = 0; d < 64; d++) acc[d] = 0.0f;

    for (int bi = 0; bi < NBLK; bi++) {
        const float* krow = k + (size_t)(h * TT + bi * 64 + r) * HDIM;
        const float* vrow = v + (size_t)(h * TT + bi * 64 + r) * HDIM;
        #pragma unroll
        for (int d = 0; d < 64; d += 4) {
            *(float4*)(&Ks[r][d]) = *(const float4*)(krow + d);
            *(float4*)(&Vs[r][d]) = *(const float4*)(vrow + d);
        }
        Ms[r] = (float)mask[bi * 64 + r];
        __syncthreads();

        for (int j = 0; j < 64; j++) {
            float s = 0.0f;
            #pragma unroll
            for (int d = 0; d < 64; d++) s += qreg[d] * Ks[j][d];
            s *= 0.125f;
            if (Ms[j] <= 0.0f) s = NEGV;
            if (s > m) {
                float fac = __expf(m - s);
                l *= fac;
                #pragma unroll
                for (int d = 0; d < 64; d++) acc[d] *= fac;
                m = s;
            }
            float p = __expf(s - m);
            l += p;
            #pragma unroll
            for (int d = 0; d < 64; d++) acc[d] += p * Vs[j][d];
        }
        __syncthreads();
    }
    float inv = 1.0f / l;
    float* crow = ctx + (size_t)qtok * DD + h * HDIM;
    #pragma unroll
    for (int d = 0; d < 64; d++) crow[d] = acc[d] * inv;
}

// ---------------------------------------------------------------------------
// LayerNorm (biased var, eps=1e-12), in place on hs[T,D].
// ---------------------------------------------------------------------------
__global__ __launch_bounds__(256) void ln_k(
    float* __restrict__ hs, const float* __restrict__ g,
    const float* __restrict__ b)
{
    int t = blockIdx.x;
    int tid = threadIdx.x;
    __shared__ float red[256];

    float x0 = hs[t * DD + tid];
    float x1 = hs[t * DD + tid + 256];
    float x2 = hs[t * DD + tid + 512];

    red[tid] = x0 + x1 + x2;
    __syncthreads();
    for (int off = 128; off > 0; off >>= 1) {
        if (tid < off) red[tid] += red[tid + off];
        __syncthreads();
    }
    float mean = red[0] * (1.0f / 768.0f);
    __syncthreads();

    float d0 = x0 - mean, d1 = x1 - mean, d2 = x2 - mean;
    red[tid] = d0 * d0 + d1 * d1 + d2 * d2;
    __syncthreads();
    for (int off = 128; off > 0; off >>= 1) {
        if (tid < off) red[tid] += red[tid + off];
        __syncthreads();
    }
    float var = red[0] * (1.0f / 768.0f);
    float rstd = rsqrtf(var + 1e-12f);

    hs[t * DD + tid]       = d0 * rstd * g[tid]       + b[tid];
    hs[t * DD + tid + 256] = d1 * rstd * g[tid + 256] + b[tid + 256];
    hs[t * DD + tid + 512] = d2 * rstd * g[tid + 512] + b[tid + 512];
}

// ---------------------------------------------------------------------------
// Final projection: out[T,16] = hs[T,768] @ Wc[768,16] + bc
// ---------------------------------------------------------------------------
__global__ __launch_bounds__(256) void out_gemm_k(
    const float* __restrict__ hs, const float* __restrict__ Wc,
    const float* __restrict__ bc, float* __restrict__ out)
{
    int c = threadIdx.x & 15;
    int rl = threadIdx.x >> 4;
    int t = blockIdx.x * 16 + rl;
    float acc = bc[c];
    for (int kk = 0; kk < DD; kk++)
        acc += hs[t * DD + kk] * Wc[kk * NCOUT + c];
    out[t * NCOUT + c] = acc;
}

// ---------------------------------------------------------------------------
extern "C" void kernel_launch(void* const* d_in, const int* in_sizes, int n_in,
                              void* d_out, int out_size, void* d_ws, size_t ws_size,
                              hipStream_t stream)
{
    const float* hidden = (const float*)d_in[0];
    const int*   mask   = (const int*)d_in[1];
    const int*   rnd    = (const int*)d_in[2];
    const float* Wq = (const float*)d_in[3];
    const float* bq = (const float*)d_in[4];
    const float* Wk = (const float*)d_in[5];
    const float* bk = (const float*)d_in[6];
    const float* Wv = (const float*)d_in[7];
    const float* bv = (const float*)d_in[8];
    const float* Wo = (const float*)d_in[9];
    const float* bo = (const float*)d_in[10];
    const float* Wd = (const float*)d_in[11];
    const float* bd = (const float*)d_in[12];
    const float* lng = (const float*)d_in[13];
    const float* lnb = (const float*)d_in[14];
    const float* Wc = (const float*)d_in[15];
    const float* bc = (const float*)d_in[16];
    float* out = (float*)d_out;

    // Only the LAST layer's hidden state reaches the output (out = hs[-1]).
    int L = in_sizes[0] / (TT * DD);
    const float* X = hidden + (size_t)(L - 1) * TT * DD;

    float* ws = (float*)d_ws;
    const size_t HSZ = (size_t)NHEAD * TT * HDIM;   // 786432 floats
    const size_t TDS = (size_t)TT * DD;             // 786432 floats
    float* q    = ws;
    float* k    = q + HSZ;
    float* v    = k + HSZ;
    float* ctx  = v + HSZ;
    float* attn = ctx + TDS;
    float* hs   = attn + TDS;

    qkv_gemm_k<<<dim3(16, NHEAD, 3), 256, 0, stream>>>(X, Wq, bq, Wk, bk, Wv, bv, q, k, v);
    attn_mid_k<<<dim3(NMID, NHEAD), 64, 0, stream>>>(q, k, v, mask, rnd, ctx);
    attn_glob_k<<<dim3(2, NHEAD), 64, 0, stream>>>(q, k, v, mask, ctx);
    gemm_bias_k<<<dim3(16, NHEAD), 256, 0, stream>>>(ctx, Wo, bo, attn);
    gemm_bias_k<<<dim3(16, NHEAD), 256, 0, stream>>>(attn, Wd, bd, hs);
    ln_k<<<TT, 256, 0, stream>>>(hs, lng, lnb);
    out_gemm_k<<<64, 256, 0, stream>>>(hs, Wc, bc, out);
}

// Round 2
// 517.094 us; speedup vs baseline: 2.3079x; 2.3079x over previous
//
#include <hip/hip_runtime.h>
#include <hip/hip_bf16.h>
#include <math.h>

#define TT    1024   // B*S tokens
#define DD    768    // hidden dim
#define NHEAD 12
#define HDIM  64
#define NBLK  16     // T / 64
#define NMID  14     // NBLK - 2
#define NCOUT 16

// ---------------------------------------------------------------------------
// QKV projection: X[T,D] @ {Wq,Wk,Wv}[D,D] + bias, scattered to [H][T][64]
// ---------------------------------------------------------------------------
__global__ __launch_bounds__(256) void qkv_gemm_k(
    const float* __restrict__ X,
    const float* __restrict__ Wq, const float* __restrict__ bq,
    const float* __restrict__ Wk, const float* __restrict__ bk,
    const float* __restrict__ Wv, const float* __restrict__ bv,
    float* __restrict__ qo, float* __restrict__ ko, float* __restrict__ vo)
{
    const float* W; const float* bias; float* out;
    if (blockIdx.z == 0)      { W = Wq; bias = bq; out = qo; }
    else if (blockIdx.z == 1) { W = Wk; bias = bk; out = ko; }
    else                      { W = Wv; bias = bv; out = vo; }

    __shared__ float As[16][65];
    __shared__ float Bs[16][65];
    int tid = threadIdx.x;
    int tx = tid & 15, ty = tid >> 4;
    int row0 = blockIdx.x * 64;
    int head = blockIdx.y;          // col tile == head (64-wide)
    int col0 = head * 64;
    float acc[4][4] = {};

    for (int k0 = 0; k0 < DD; k0 += 16) {
        #pragma unroll
        for (int i = 0; i < 4; i++) {
            int e = tid + i * 256;
            int r = e >> 4, kk = e & 15;
            As[kk][r] = X[(row0 + r) * DD + k0 + kk];
        }
        #pragma unroll
        for (int i = 0; i < 4; i++) {
            int e = tid + i * 256;
            int kk = e >> 6, c = e & 63;
            Bs[kk][c] = W[(k0 + kk) * DD + col0 + c];
        }
        __syncthreads();
        #pragma unroll
        for (int kk = 0; kk < 16; kk++) {
            float a[4], b[4];
            #pragma unroll
            for (int i = 0; i < 4; i++) a[i] = As[kk][ty * 4 + i];
            #pragma unroll
            for (int j = 0; j < 4; j++) b[j] = Bs[kk][tx * 4 + j];
            #pragma unroll
            for (int i = 0; i < 4; i++)
                #pragma unroll
                for (int j = 0; j < 4; j++)
                    acc[i][j] += a[i] * b[j];
        }
        __syncthreads();
    }
    #pragma unroll
    for (int i = 0; i < 4; i++) {
        int r = row0 + ty * 4 + i;
        #pragma unroll
        for (int j = 0; j < 4; j++) {
            int d = tx * 4 + j;
            out[(head * TT + r) * HDIM + d] = acc[i][j] + bias[col0 + d];
        }
    }
}

// ---------------------------------------------------------------------------
// Generic GEMM: C[T,D] = A[T,D] @ W[D,D] + bias
// ---------------------------------------------------------------------------
__global__ __launch_bounds__(256) void gemm_bias_k(
    const float* __restrict__ A, const float* __restrict__ W,
    const float* __restrict__ bias, float* __restrict__ C)
{
    __shared__ float As[16][65];
    __shared__ float Bs[16][65];
    int tid = threadIdx.x;
    int tx = tid & 15, ty = tid >> 4;
    int row0 = blockIdx.x * 64;
    int col0 = blockIdx.y * 64;
    float acc[4][4] = {};

    for (int k0 = 0; k0 < DD; k0 += 16) {
        #pragma unroll
        for (int i = 0; i < 4; i++) {
            int e = tid + i * 256;
            int r = e >> 4, kk = e & 15;
            As[kk][r] = A[(row0 + r) * DD + k0 + kk];
        }
        #pragma unroll
        for (int i = 0; i < 4; i++) {
            int e = tid + i * 256;
            int kk = e >> 6, c = e & 63;
            Bs[kk][c] = W[(k0 + kk) * DD + col0 + c];
        }
        __syncthreads();
        #pragma unroll
        for (int kk = 0; kk < 16; kk++) {
            float a[4], b[4];
            #pragma unroll
            for (int i = 0; i < 4; i++) a[i] = As[kk][ty * 4 + i];
            #pragma unroll
            for (int j = 0; j < 4; j++) b[j] = Bs[kk][tx * 4 + j];
            #pragma unroll
            for (int i = 0; i < 4; i++)
                #pragma unroll
                for (int j = 0; j < 4; j++)
                    acc[i][j] += a[i] * b[j];
        }
        __syncthreads();
    }
    #pragma unroll
    for (int i = 0; i < 4; i++) {
        int r = row0 + ty * 4 + i;
        #pragma unroll
        for (int j = 0; j < 4; j++) {
            int c = col0 + tx * 4 + j;
            C[r * DD + c] = acc[i][j] + bias[c];
        }
    }
}

// ---------------------------------------------------------------------------
// Shared inner loop: accumulate exp-weighted V over one 64-key block.
// Scores are small (0.02-scale weights) and masked keys contribute p=0
// exactly, so softmax without max-subtraction is numerically safe and
// removes the serial rescale chain.
// ---------------------------------------------------------------------------
__device__ __forceinline__ void attn_block_accum(
    const float* __restrict__ k, const float* __restrict__ v,
    const int* __restrict__ mask, int h, int bi,
    const float qreg[64], float& l, float acc[64])
{
    const float* kb = k + (size_t)(h * TT + bi * 64) * HDIM;
    const float* vb = v + (size_t)(h * TT + bi * 64) * HDIM;
    const int* mb = mask + bi * 64;
    for (int j = 0; j < 64; j++) {
        const float* kr = kb + j * 64;
        float s0 = 0.f, s1 = 0.f, s2 = 0.f, s3 = 0.f;
        #pragma unroll
        for (int d = 0; d < 64; d += 4) {
            float4 t = *(const float4*)(kr + d);
            s0 += qreg[d] * t.x; s1 += qreg[d + 1] * t.y;
            s2 += qreg[d + 2] * t.z; s3 += qreg[d + 3] * t.w;
        }
        float s = (s0 + s1) + (s2 + s3);
        float p = (mb[j] > 0) ? __expf(s * 0.125f) : 0.f;
        l += p;
        const float* vr = vb + j * 64;
        #pragma unroll
        for (int d = 0; d < 64; d += 4) {
            float4 t = *(const float4*)(vr + d);
            acc[d] += p * t.x; acc[d + 1] += p * t.y;
            acc[d + 2] += p * t.z; acc[d + 3] += p * t.w;
        }
    }
}

// ---------------------------------------------------------------------------
// Mid-block sparse attention. Block = 256 threads = 4 waves per (n, h).
// Wave w handles 2 of the 8 gathered key blocks; in-block LDS merge.
// ---------------------------------------------------------------------------
__global__ __launch_bounds__(256) void attn_mid_k(
    const float* __restrict__ q, const float* __restrict__ k,
    const float* __restrict__ v, const int* __restrict__ mask,
    const int* __restrict__ rnd, float* __restrict__ ctx)
{
    int n = blockIdx.x;            // 0..13
    int h = blockIdx.y;
    int w = threadIdx.x >> 6;      // wave 0..3
    int r = threadIdx.x & 63;      // query row in block
    __shared__ float mrg[3][64][65];   // bank-conflict-free merge buffer

    int qtok = (n + 1) * 64 + r;
    float qreg[64];
    const float* qrow = q + (size_t)(h * TT + qtok) * HDIM;
    #pragma unroll
    for (int d = 0; d < 64; d += 4) {
        float4 t = *(const float4*)(qrow + d);
        qreg[d] = t.x; qreg[d + 1] = t.y; qreg[d + 2] = t.z; qreg[d + 3] = t.w;
    }

    int b0, b1;
    if (w == 0)      { b0 = 0;                b1 = NBLK - 1;        }
    else if (w == 1) { b0 = n;                b1 = n + 1;           }
    else if (w == 2) { b0 = n + 2;            b1 = rnd[n * 3 + 0];  }
    else             { b0 = rnd[n * 3 + 1];   b1 = rnd[n * 3 + 2];  }

    float l = 0.f;
    float acc[64];
    #pragma unroll
    for (int d = 0; d < 64; d++) acc[d] = 0.f;

    attn_block_accum(k, v, mask, h, b0, qreg, l, acc);
    attn_block_accum(k, v, mask, h, b1, qreg, l, acc);

    if (w > 0) {
        #pragma unroll
        for (int d = 0; d < 64; d++) mrg[w - 1][r][d] = acc[d];
        mrg[w - 1][r][64] = l;
    }
    __syncthreads();
    if (w == 0) {
        #pragma unroll
        for (int ww = 0; ww < 3; ww++) {
            l += mrg[ww][r][64];
            #pragma unroll
            for (int d = 0; d < 64; d++) acc[d] += mrg[ww][r][d];
        }
        float inv = 1.f / l;
        float* crow = ctx + (size_t)qtok * DD + h * HDIM;
        #pragma unroll
        for (int d = 0; d < 64; d += 4) {
            float4 t;
            t.x = acc[d] * inv; t.y = acc[d + 1] * inv;
            t.z = acc[d + 2] * inv; t.w = acc[d + 3] * inv;
            *(float4*)(crow + d) = t;
        }
    }
}

// ---------------------------------------------------------------------------
// Global attention (query blocks 0 and 15 over all keys), partial pass.
// Grid (2, H, 4); block = 4 waves; wave w handles key block z*4+w.
// In-block merge -> one partial (l, acc[64]) per (g,h,z,row).
// ---------------------------------------------------------------------------
__global__ __launch_bounds__(256) void attn_glob_k(
    const float* __restrict__ q, const float* __restrict__ k,
    const float* __restrict__ v, const int* __restrict__ mask,
    float* __restrict__ pacc, float* __restrict__ pl)
{
    int g = blockIdx.x;
    int h = blockIdx.y;
    int z = blockIdx.z;            // key chunk 0..3
    int w = threadIdx.x >> 6;
    int r = threadIdx.x & 63;
    __shared__ float mrg[3][64][65];

    int qb = g ? (NBLK - 1) : 0;
    int qtok = qb * 64 + r;
    float qreg[64];
    const float* qrow = q + (size_t)(h * TT + qtok) * HDIM;
    #pragma unroll
    for (int d = 0; d < 64; d += 4) {
        float4 t = *(const float4*)(qrow + d);
        qreg[d] = t.x; qreg[d + 1] = t.y; qreg[d + 2] = t.z; qreg[d + 3] = t.w;
    }

    float l = 0.f;
    float acc[64];
    #pragma unroll
    for (int d = 0; d < 64; d++) acc[d] = 0.f;

    attn_block_accum(k, v, mask, h, z * 4 + w, qreg, l, acc);

    if (w > 0) {
        #pragma unroll
        for (int d = 0; d < 64; d++) mrg[w - 1][r][d] = acc[d];
        mrg[w - 1][r][64] = l;
    }
    __syncthreads();
    if (w == 0) {
        #pragma unroll
        for (int ww = 0; ww < 3; ww++) {
            l += mrg[ww][r][64];
            #pragma unroll
            for (int d = 0; d < 64; d++) acc[d] += mrg[ww][r][d];
        }
        int idx = ((g * NHEAD + h) * 4 + z) * 64 + r;
        pl[idx] = l;
        float* prow = pacc + (size_t)idx * 64;
        #pragma unroll
        for (int d = 0; d < 64; d += 4) {
            float4 t; t.x = acc[d]; t.y = acc[d + 1]; t.z = acc[d + 2]; t.w = acc[d + 3];
            *(float4*)(prow + d) = t;
        }
    }
}

// Combine 4 partials per (g,h) row and write ctx.
__global__ __launch_bounds__(64) void glob_comb_k(
    const float* __restrict__ pacc, const float* __restrict__ pl,
    float* __restrict__ ctx)
{
    int g = blockIdx.x;
    int h = blockIdx.y;
    int r = threadIdx.x;
    int qb = g ? (NBLK - 1) : 0;
    int qtok = qb * 64 + r;

    float l = 0.f;
    float acc[64];
    #pragma unroll
    for (int d = 0; d < 64; d++) acc[d] = 0.f;
    for (int z = 0; z < 4; z++) {
        int idx = ((g * NHEAD + h) * 4 + z) * 64 + r;
        l += pl[idx];
        const float* prow = pacc + (size_t)idx * 64;
        #pragma unroll
        for (int d = 0; d < 64; d += 4) {
            float4 t = *(const float4*)(prow + d);
            acc[d] += t.x; acc[d + 1] += t.y; acc[d + 2] += t.z; acc[d + 3] += t.w;
        }
    }
    float inv = 1.f / l;
    float* crow = ctx + (size_t)qtok * DD + h * HDIM;
    #pragma unroll
    for (int d = 0; d < 64; d += 4) {
        float4 t;
        t.x = acc[d] * inv; t.y = acc[d + 1] * inv;
        t.z = acc[d + 2] * inv; t.w = acc[d + 3] * inv;
        *(float4*)(crow + d) = t;
    }
}

// ---------------------------------------------------------------------------
// LayerNorm (biased var, eps=1e-12), in place on hs[T,D].
// ---------------------------------------------------------------------------
__global__ __launch_bounds__(256) void ln_k(
    float* __restrict__ hs, const float* __restrict__ g,
    const float* __restrict__ b)
{
    int t = blockIdx.x;
    int tid = threadIdx.x;
    __shared__ float red[256];

    float x0 = hs[t * DD + tid];
    float x1 = hs[t * DD + tid + 256];
    float x2 = hs[t * DD + tid + 512];

    red[tid] = x0 + x1 + x2;
    __syncthreads();
    for (int off = 128; off > 0; off >>= 1) {
        if (tid < off) red[tid] += red[tid + off];
        __syncthreads();
    }
    float mean = red[0] * (1.0f / 768.0f);
    __syncthreads();

    float d0 = x0 - mean, d1 = x1 - mean, d2 = x2 - mean;
    red[tid] = d0 * d0 + d1 * d1 + d2 * d2;
    __syncthreads();
    for (int off = 128; off > 0; off >>= 1) {
        if (tid < off) red[tid] += red[tid + off];
        __syncthreads();
    }
    float var = red[0] * (1.0f / 768.0f);
    float rstd = rsqrtf(var + 1e-12f);

    hs[t * DD + tid]       = d0 * rstd * g[tid]       + b[tid];
    hs[t * DD + tid + 256] = d1 * rstd * g[tid + 256] + b[tid + 256];
    hs[t * DD + tid + 512] = d2 * rstd * g[tid + 512] + b[tid + 512];
}

// ---------------------------------------------------------------------------
// Final projection: out[T,16] = hs[T,768] @ Wc[768,16] + bc
// ---------------------------------------------------------------------------
__global__ __launch_bounds__(256) void out_gemm_k(
    const float* __restrict__ hs, const float* __restrict__ Wc,
    const float* __restrict__ bc, float* __restrict__ out)
{
    int c = threadIdx.x & 15;
    int rl = threadIdx.x >> 4;
    int t = blockIdx.x * 16 + rl;
    float acc = bc[c];
    for (int kk = 0; kk < DD; kk++)
        acc += hs[t * DD + kk] * Wc[kk * NCOUT + c];
    out[t * NCOUT + c] = acc;
}

// ---------------------------------------------------------------------------
extern "C" void kernel_launch(void* const* d_in, const int* in_sizes, int n_in,
                              void* d_out, int out_size, void* d_ws, size_t ws_size,
                              hipStream_t stream)
{
    const float* hidden = (const float*)d_in[0];
    const int*   mask   = (const int*)d_in[1];
    const int*   rnd    = (const int*)d_in[2];
    const float* Wq = (const float*)d_in[3];
    const float* bq = (const float*)d_in[4];
    const float* Wk = (const float*)d_in[5];
    const float* bk = (const float*)d_in[6];
    const float* Wv = (const float*)d_in[7];
    const float* bv = (const float*)d_in[8];
    const float* Wo = (const float*)d_in[9];
    const float* bo = (const float*)d_in[10];
    const float* Wd = (const float*)d_in[11];
    const float* bd = (const float*)d_in[12];
    const float* lng = (const float*)d_in[13];
    const float* lnb = (const float*)d_in[14];
    const float* Wc = (const float*)d_in[15];
    const float* bc = (const float*)d_in[16];
    float* out = (float*)d_out;

    // Only the LAST layer's hidden state reaches the output (out = hs[-1]).
    int L = in_sizes[0] / (TT * DD);
    const float* X = hidden + (size_t)(L - 1) * TT * DD;

    float* ws = (float*)d_ws;
    const size_t HSZ = (size_t)NHEAD * TT * HDIM;   // 786432 floats
    const size_t TDS = (size_t)TT * DD;             // 786432 floats
    float* q    = ws;
    float* k    = q + HSZ;
    float* v    = k + HSZ;
    float* ctx  = v + HSZ;
    float* attn = ctx + TDS;
    float* hs   = attn + TDS;
    float* pacc = hs + TDS;                          // 2*12*4*64*64 = 393216
    float* pl   = pacc + (size_t)2 * NHEAD * 4 * 64 * 64;   // 6144

    qkv_gemm_k<<<dim3(16, NHEAD, 3), 256, 0, stream>>>(X, Wq, bq, Wk, bk, Wv, bv, q, k, v);
    attn_mid_k<<<dim3(NMID, NHEAD), 256, 0, stream>>>(q, k, v, mask, rnd, ctx);
    attn_glob_k<<<dim3(2, NHEAD, 4), 256, 0, stream>>>(q, k, v, mask, pacc, pl);
    glob_comb_k<<<dim3(2, NHEAD), 64, 0, stream>>>(pacc, pl, ctx);
    gemm_bias_k<<<dim3(16, NHEAD), 256, 0, stream>>>(ctx, Wo, bo, attn);
    gemm_bias_k<<<dim3(16, NHEAD), 256, 0, stream>>>(attn, Wd, bd, hs);
    ln_k<<<TT, 256, 0, stream>>>(hs, lng, lnb);
    out_gemm_k<<<64, 256, 0, stream>>>(hs, Wc, bc, out);
}

// Round 3
// 141.089 us; speedup vs baseline: 8.4585x; 3.6650x over previous
//
#include <hip/hip_runtime.h>
#include <hip/hip_bf16.h>
#include <math.h>

#define TT    1024   // B*S tokens
#define DD    768    // hidden dim
#define NHEAD 12
#define HDIM  64
#define NBLK  16
#define NMID  14
#define NCOUT 16

typedef __attribute__((ext_vector_type(4))) float f32x4;
typedef __attribute__((ext_vector_type(8))) short bfrag;   // 8 bf16 = 4 VGPRs

#define MFMA(a, b, c) __builtin_amdgcn_mfma_f32_16x16x32_bf16(a, b, c, 0, 0, 0)

__device__ __forceinline__ bfrag ldg8(const ushort* p) { return *(const bfrag*)p; }
__device__ __forceinline__ ushort f2bf(float f) {
    __hip_bfloat16 h = __float2bfloat16(f);
    return *(ushort*)&h;
}

// ---------------------------------------------------------------------------
// Prep: X (last layer) fp32 -> bf16, row-major copy.
// ---------------------------------------------------------------------------
__global__ __launch_bounds__(256) void prep_x_k(const float* __restrict__ X,
                                                ushort* __restrict__ xb)
{
    int i = blockIdx.x * 256 + threadIdx.x;          // float4 index
    float4 t = ((const float4*)X)[i];
    ushort4 u;
    u.x = f2bf(t.x); u.y = f2bf(t.y); u.z = f2bf(t.z); u.w = f2bf(t.w);
    ((ushort4*)xb)[i] = u;
}

// ---------------------------------------------------------------------------
// Prep: transpose + convert the 5 weight matrices W[k][n] -> WT[n][k] bf16.
// Grid (24,24,5), 32x32 LDS tile transpose.
// ---------------------------------------------------------------------------
__global__ __launch_bounds__(256) void prep_wt_k(
    const float* __restrict__ Wq, const float* __restrict__ Wk,
    const float* __restrict__ Wv, const float* __restrict__ Wo,
    const float* __restrict__ Wd,
    ushort* __restrict__ qT, ushort* __restrict__ kT, ushort* __restrict__ vT,
    ushort* __restrict__ oT, ushort* __restrict__ dT)
{
    __shared__ float t[32][33];
    int z = blockIdx.z;
    const float* W; ushort* O;
    if (z == 0)      { W = Wq; O = qT; }
    else if (z == 1) { W = Wk; O = kT; }
    else if (z == 2) { W = Wv; O = vT; }
    else if (z == 3) { W = Wo; O = oT; }
    else             { W = Wd; O = dT; }
    int k0 = blockIdx.x * 32, n0 = blockIdx.y * 32;
    int tx = threadIdx.x & 31, ty = threadIdx.x >> 5;   // ty 0..7
    #pragma unroll
    for (int i = 0; i < 4; i++)
        t[ty + i * 8][tx] = W[(k0 + ty + i * 8) * DD + n0 + tx];
    __syncthreads();
    #pragma unroll
    for (int i = 0; i < 4; i++)
        O[(n0 + ty + i * 8) * DD + k0 + tx] = f2bf(t[tx][ty + i * 8]);
}

// ---------------------------------------------------------------------------
// QKV MFMA GEMM: xb[1024][768] @ W^T -> q,k [H][T][64], v as vT [H][64][T].
// Grid (16, 12, 3); 4 waves, each 32x32 of a 64x64 tile. No LDS.
// ---------------------------------------------------------------------------
__global__ __launch_bounds__(256) void qkv_mfma_k(
    const ushort* __restrict__ xb,
    const ushort* __restrict__ wqT, const ushort* __restrict__ wkT,
    const ushort* __restrict__ wvT,
    const float* __restrict__ bq, const float* __restrict__ bk,
    const float* __restrict__ bv,
    ushort* __restrict__ qo, ushort* __restrict__ ko, ushort* __restrict__ vTo)
{
    int z = blockIdx.z;
    const ushort* BT = (z == 0) ? wqT : (z == 1) ? wkT : wvT;
    const float* bias = (z == 0) ? bq : (z == 1) ? bk : bv;

    int lane = threadIdx.x & 63, w = threadIdx.x >> 6;
    int lr = lane & 15, lg = lane >> 4;
    int row0 = blockIdx.x * 64 + (w >> 1) * 32;
    int h = blockIdx.y;
    int col0 = h * 64 + (w & 1) * 32;

    f32x4 acc00 = {0,0,0,0}, acc01 = {0,0,0,0}, acc10 = {0,0,0,0}, acc11 = {0,0,0,0};
    const ushort* a0p = xb + (size_t)(row0 + lr) * DD + lg * 8;
    const ushort* a1p = a0p + 16 * DD;
    const ushort* b0p = BT + (size_t)(col0 + lr) * DD + lg * 8;
    const ushort* b1p = b0p + 16 * DD;
    #pragma unroll 4
    for (int k0 = 0; k0 < DD; k0 += 32) {
        bfrag a0 = ldg8(a0p + k0), a1 = ldg8(a1p + k0);
        bfrag b0 = ldg8(b0p + k0), b1 = ldg8(b1p + k0);
        acc00 = MFMA(a0, b0, acc00); acc01 = MFMA(a0, b1, acc01);
        acc10 = MFMA(a1, b0, acc10); acc11 = MFMA(a1, b1, acc11);
    }
    #pragma unroll
    for (int mt = 0; mt < 2; mt++) {
        #pragma unroll
        for (int nt = 0; nt < 2; nt++) {
            f32x4 acc = (mt == 0) ? (nt == 0 ? acc00 : acc01)
                                  : (nt == 0 ? acc10 : acc11);
            #pragma unroll
            for (int j = 0; j < 4; j++) {
                int r = row0 + mt * 16 + lg * 4 + j;
                int c = col0 + nt * 16 + lr;            // global col
                ushort u = f2bf(acc[j] + bias[c]);
                int cc = c - h * 64;                    // col within head
                if (z == 2)      vTo[(size_t)(h * 64 + cc) * TT + r] = u;
                else if (z == 0) qo[(size_t)(h * TT + r) * 64 + cc] = u;
                else             ko[(size_t)(h * TT + r) * 64 + cc] = u;
            }
        }
    }
}

// ---------------------------------------------------------------------------
// Generic MFMA GEMM: A[1024][768] bf16 @ BT (pre-transposed) + bias.
// OUTF32=0 -> bf16 out, OUTF32=1 -> f32 out. Grid (16,12).
// ---------------------------------------------------------------------------
template <int OUTF32>
__global__ __launch_bounds__(256) void mm_mfma_k(
    const ushort* __restrict__ A, const ushort* __restrict__ BT,
    const float* __restrict__ bias, void* __restrict__ out)
{
    int lane = threadIdx.x & 63, w = threadIdx.x >> 6;
    int lr = lane & 15, lg = lane >> 4;
    int row0 = blockIdx.x * 64 + (w >> 1) * 32;
    int col0 = blockIdx.y * 64 + (w & 1) * 32;

    f32x4 acc00 = {0,0,0,0}, acc01 = {0,0,0,0}, acc10 = {0,0,0,0}, acc11 = {0,0,0,0};
    const ushort* a0p = A + (size_t)(row0 + lr) * DD + lg * 8;
    const ushort* a1p = a0p + 16 * DD;
    const ushort* b0p = BT + (size_t)(col0 + lr) * DD + lg * 8;
    const ushort* b1p = b0p + 16 * DD;
    #pragma unroll 4
    for (int k0 = 0; k0 < DD; k0 += 32) {
        bfrag a0 = ldg8(a0p + k0), a1 = ldg8(a1p + k0);
        bfrag b0 = ldg8(b0p + k0), b1 = ldg8(b1p + k0);
        acc00 = MFMA(a0, b0, acc00); acc01 = MFMA(a0, b1, acc01);
        acc10 = MFMA(a1, b0, acc10); acc11 = MFMA(a1, b1, acc11);
    }
    #pragma unroll
    for (int mt = 0; mt < 2; mt++) {
        #pragma unroll
        for (int nt = 0; nt < 2; nt++) {
            f32x4 acc = (mt == 0) ? (nt == 0 ? acc00 : acc01)
                                  : (nt == 0 ? acc10 : acc11);
            #pragma unroll
            for (int j = 0; j < 4; j++) {
                int r = row0 + mt * 16 + lg * 4 + j;
                int c = col0 + nt * 16 + lr;
                float v = acc[j] + bias[c];
                if (OUTF32) ((float*)out)[(size_t)r * DD + c] = v;
                else        ((ushort*)out)[(size_t)r * DD + c] = f2bf(v);
            }
        }
    }
}

// ---------------------------------------------------------------------------
// Attention wave core: 16 q-rows vs 8 gathered key blocks (512 keys).
// S = Q K^T via MFMA -> scale/mask/exp -> P (bf16, swizzled per-wave LDS)
// -> O = P V via MFMA (vT gives contiguous B-frags). lsum = row denominators.
// No cross-wave communication; no __syncthreads.
// ---------------------------------------------------------------------------
__device__ __forceinline__ void attn_core(
    const ushort* __restrict__ qbf, const ushort* __restrict__ kbf,
    const ushort* __restrict__ vT, const int* __restrict__ mask,
    const int kblk[8], int h, int qtok0, ushort* __restrict__ Pw,
    f32x4 (&o)[4], float (&lsum)[4])
{
    int lane = threadIdx.x & 63, lr = lane & 15, lg = lane >> 4;
    const ushort* qrow = qbf + (size_t)(h * TT + qtok0 + lr) * 64 + lg * 8;
    bfrag aq0 = ldg8(qrow);
    bfrag aq1 = ldg8(qrow + 32);

    lsum[0] = lsum[1] = lsum[2] = lsum[3] = 0.f;
    #pragma unroll
    for (int kb = 0; kb < 8; kb++) {
        int bi = kblk[kb];
        #pragma unroll
        for (int kt = 0; kt < 4; kt++) {
            int key = bi * 64 + kt * 16 + lr;
            const ushort* krow = kbf + (size_t)(h * TT + key) * 64 + lg * 8;
            bfrag b0 = ldg8(krow);
            bfrag b1 = ldg8(krow + 32);
            f32x4 s = {0, 0, 0, 0};
            s = MFMA(aq0, b0, s);
            s = MFMA(aq1, b1, s);
            int mk = mask[key];
            #pragma unroll
            for (int j = 0; j < 4; j++) {
                float pv = (mk > 0) ? __expf(s[j] * 0.125f) : 0.0f;
                lsum[j] += pv;
                int row = lg * 4 + j;
                int idx = (row * 512 + (kb * 4 + kt) * 16 + lr) ^ ((row & 7) << 3);
                Pw[idx] = f2bf(pv);
            }
        }
    }
    #pragma unroll
    for (int j = 0; j < 4; j++) {
        float l = lsum[j];
        l += __shfl_xor(l, 1); l += __shfl_xor(l, 2);
        l += __shfl_xor(l, 4); l += __shfl_xor(l, 8);
        lsum[j] = l;
    }
    f32x4 zero = {0, 0, 0, 0};
    o[0] = zero; o[1] = zero; o[2] = zero; o[3] = zero;
    #pragma unroll
    for (int ks = 0; ks < 16; ks++) {          // 32-key chunks of gathered axis
        int bi = kblk[ks >> 1];
        int pidx = (lr * 512 + ks * 32 + lg * 8) ^ ((lr & 7) << 3);
        bfrag pa = *(const bfrag*)(Pw + pidx);
        #pragma unroll
        for (int dt = 0; dt < 4; dt++) {
            const ushort* vrow = vT + (size_t)(h * 64 + dt * 16 + lr) * TT
                               + bi * 64 + (ks & 1) * 32 + lg * 8;
            o[dt] = MFMA(pa, ldg8(vrow), o[dt]);
        }
    }
}

// Mid-block attention: grid (14, 12), 4 waves (one per 16-q-row tile).
__global__ __launch_bounds__(256) void attn_mid_k(
    const ushort* __restrict__ qbf, const ushort* __restrict__ kbf,
    const ushort* __restrict__ vT, const int* __restrict__ mask,
    const int* __restrict__ rnd, ushort* __restrict__ ctx)
{
    __shared__ ushort P[4][16 * 512];
    int n = blockIdx.x, h = blockIdx.y, w = threadIdx.x >> 6;
    int lane = threadIdx.x & 63, lr = lane & 15, lg = lane >> 4;
    int kblk[8] = { 0, NBLK - 1, n, n + 1, n + 2,
                    rnd[n * 3 + 0], rnd[n * 3 + 1], rnd[n * 3 + 2] };
    int qtok0 = (n + 1) * 64 + w * 16;
    f32x4 o[4]; float l[4];
    attn_core(qbf, kbf, vT, mask, kblk, h, qtok0, &P[w][0], o, l);
    float inv[4];
    #pragma unroll
    for (int j = 0; j < 4; j++) inv[j] = 1.0f / l[j];
    #pragma unroll
    for (int dt = 0; dt < 4; dt++)
        #pragma unroll
        for (int j = 0; j < 4; j++)
            ctx[(size_t)(qtok0 + lg * 4 + j) * DD + h * 64 + dt * 16 + lr] =
                f2bf(o[dt][j] * inv[j]);
}

// Global attention partials: grid (2, 12, 2); z covers key blocks z*8..z*8+7.
__global__ __launch_bounds__(256) void attn_glob_k(
    const ushort* __restrict__ qbf, const ushort* __restrict__ kbf,
    const ushort* __restrict__ vT, const int* __restrict__ mask,
    float* __restrict__ pacc, float* __restrict__ pl)
{
    __shared__ ushort P[4][16 * 512];
    int g = blockIdx.x, h = blockIdx.y, z = blockIdx.z, w = threadIdx.x >> 6;
    int lane = threadIdx.x & 63, lr = lane & 15, lg = lane >> 4;
    int kblk[8];
    #pragma unroll
    for (int kb = 0; kb < 8; kb++) kblk[kb] = z * 8 + kb;
    int qtok0 = (g ? (NBLK - 1) : 0) * 64 + w * 16;
    f32x4 o[4]; float l[4];
    attn_core(qbf, kbf, vT, mask, kblk, h, qtok0, &P[w][0], o, l);
    int pb = (g * NHEAD + h) * 2 + z;
    #pragma unroll
    for (int dt = 0; dt < 4; dt++)
        #pragma unroll
        for (int j = 0; j < 4; j++)
            pacc[((size_t)pb * 64 + (w * 16 + lg * 4 + j)) * 64 + dt * 16 + lr] = o[dt][j];
    if (lr == 0) {
        #pragma unroll
        for (int j = 0; j < 4; j++)
            pl[pb * 64 + w * 16 + lg * 4 + j] = l[j];
    }
}

// Combine the two z-partials per (g,h) and write ctx (bf16).
__global__ __launch_bounds__(64) void glob_comb_k(
    const float* __restrict__ pacc, const float* __restrict__ pl,
    ushort* __restrict__ ctx)
{
    int g = blockIdx.x, h = blockIdx.y, r = threadIdx.x;
    int qtok = (g ? (NBLK - 1) : 0) * 64 + r;
    int pb0 = (g * NHEAD + h) * 2;
    float l = pl[pb0 * 64 + r] + pl[(pb0 + 1) * 64 + r];
    float inv = 1.0f / l;
    const float* o0 = pacc + ((size_t)pb0 * 64 + r) * 64;
    const float* o1 = pacc + ((size_t)(pb0 + 1) * 64 + r) * 64;
    #pragma unroll
    for (int d = 0; d < 64; d++)
        ctx[(size_t)qtok * DD + h * 64 + d] = f2bf((o0[d] + o1[d]) * inv);
}

// ---------------------------------------------------------------------------
// LayerNorm (biased var, eps=1e-12), in place on hs[T,D] (fp32).
// ---------------------------------------------------------------------------
__global__ __launch_bounds__(256) void ln_k(
    float* __restrict__ hs, const float* __restrict__ g,
    const float* __restrict__ b)
{
    int t = blockIdx.x;
    int tid = threadIdx.x;
    __shared__ float red[256];

    float x0 = hs[t * DD + tid];
    float x1 = hs[t * DD + tid + 256];
    float x2 = hs[t * DD + tid + 512];

    red[tid] = x0 + x1 + x2;
    __syncthreads();
    for (int off = 128; off > 0; off >>= 1) {
        if (tid < off) red[tid] += red[tid + off];
        __syncthreads();
    }
    float mean = red[0] * (1.0f / 768.0f);
    __syncthreads();

    float d0 = x0 - mean, d1 = x1 - mean, d2 = x2 - mean;
    red[tid] = d0 * d0 + d1 * d1 + d2 * d2;
    __syncthreads();
    for (int off = 128; off > 0; off >>= 1) {
        if (tid < off) red[tid] += red[tid + off];
        __syncthreads();
    }
    float var = red[0] * (1.0f / 768.0f);
    float rstd = rsqrtf(var + 1e-12f);

    hs[t * DD + tid]       = d0 * rstd * g[tid]       + b[tid];
    hs[t * DD + tid + 256] = d1 * rstd * g[tid + 256] + b[tid + 256];
    hs[t * DD + tid + 512] = d2 * rstd * g[tid + 512] + b[tid + 512];
}

// ---------------------------------------------------------------------------
// Final projection: out[T,16] = hs[T,768] @ Wc[768,16] + bc (fp32)
// ---------------------------------------------------------------------------
__global__ __launch_bounds__(256) void out_gemm_k(
    const float* __restrict__ hs, const float* __restrict__ Wc,
    const float* __restrict__ bc, float* __restrict__ out)
{
    int c = threadIdx.x & 15;
    int rl = threadIdx.x >> 4;
    int t = blockIdx.x * 16 + rl;
    float acc = bc[c];
    for (int kk = 0; kk < DD; kk++)
        acc += hs[t * DD + kk] * Wc[kk * NCOUT + c];
    out[t * NCOUT + c] = acc;
}

// ---------------------------------------------------------------------------
extern "C" void kernel_launch(void* const* d_in, const int* in_sizes, int n_in,
                              void* d_out, int out_size, void* d_ws, size_t ws_size,
                              hipStream_t stream)
{
    const float* hidden = (const float*)d_in[0];
    const int*   mask   = (const int*)d_in[1];
    const int*   rnd    = (const int*)d_in[2];
    const float* Wq = (const float*)d_in[3];
    const float* bq = (const float*)d_in[4];
    const float* Wk = (const float*)d_in[5];
    const float* bk = (const float*)d_in[6];
    const float* Wv = (const float*)d_in[7];
    const float* bv = (const float*)d_in[8];
    const float* Wo = (const float*)d_in[9];
    const float* bo = (const float*)d_in[10];
    const float* Wd = (const float*)d_in[11];
    const float* bd = (const float*)d_in[12];
    const float* lng = (const float*)d_in[13];
    const float* lnb = (const float*)d_in[14];
    const float* Wc = (const float*)d_in[15];
    const float* bc = (const float*)d_in[16];
    float* out = (float*)d_out;

    // Only the LAST layer's hidden state reaches the output (out = hs[-1]).
    int L = in_sizes[0] / (TT * DD);
    const float* X = hidden + (size_t)(L - 1) * TT * DD;

    const size_t TD  = (size_t)TT * DD;     // 786432
    const size_t WSZ = (size_t)DD * DD;     // 589824

    ushort* xb   = (ushort*)d_ws;
    ushort* wqT  = xb   + TD;
    ushort* wkT  = wqT  + WSZ;
    ushort* wvT  = wkT  + WSZ;
    ushort* woT  = wvT  + WSZ;
    ushort* wdT  = woT  + WSZ;
    ushort* qbf  = wdT  + WSZ;
    ushort* kbf  = qbf  + TD;
    ushort* vTb  = kbf  + TD;
    ushort* ctxb = vTb  + TD;
    ushort* attb = ctxb + TD;
    float*  hs   = (float*)(attb + TD);
    float*  pacc = hs + TD;                         // 2*12*2*64*64 = 196608
    float*  pl   = pacc + (size_t)2 * NHEAD * 2 * 64 * 64;

    prep_x_k<<<TD / 4 / 256, 256, 0, stream>>>(X, xb);
    prep_wt_k<<<dim3(24, 24, 5), 256, 0, stream>>>(Wq, Wk, Wv, Wo, Wd,
                                                   wqT, wkT, wvT, woT, wdT);
    qkv_mfma_k<<<dim3(16, NHEAD, 3), 256, 0, stream>>>(xb, wqT, wkT, wvT,
                                                       bq, bk, bv, qbf, kbf, vTb);
    attn_mid_k<<<dim3(NMID, NHEAD), 256, 0, stream>>>(qbf, kbf, vTb, mask, rnd, ctxb);
    attn_glob_k<<<dim3(2, NHEAD, 2), 256, 0, stream>>>(qbf, kbf, vTb, mask, pacc, pl);
    glob_comb_k<<<dim3(2, NHEAD), 64, 0, stream>>>(pacc, pl, ctxb);
    mm_mfma_k<0><<<dim3(16, NHEAD), 256, 0, stream>>>(ctxb, woT, bo, attb);
    mm_mfma_k<1><<<dim3(16, NHEAD), 256, 0, stream>>>(attb, wdT, bd, hs);
    ln_k<<<TT, 256, 0, stream>>>(hs, lng, lnb);
    out_gemm_k<<<64, 256, 0, stream>>>(hs, Wc, bc, out);
}

// Round 4
// 135.533 us; speedup vs baseline: 8.8053x; 1.0410x over previous
//
#include <hip/hip_runtime.h>
#include <hip/hip_bf16.h>
#include <math.h>

#define TT    1024   // B*S tokens
#define DD    768    // hidden dim
#define NHEAD 12
#define HDIM  64
#define NBLK  16
#define NMID  14
#define NCOUT 16

typedef __attribute__((ext_vector_type(4))) float f32x4;
typedef __attribute__((ext_vector_type(8))) short bfrag;   // 8 bf16 = 4 VGPRs

#define MFMA(a, b, c) __builtin_amdgcn_mfma_f32_16x16x32_bf16(a, b, c, 0, 0, 0)

__device__ __forceinline__ bfrag ldg8(const ushort* p) { return *(const bfrag*)p; }
__device__ __forceinline__ ushort f2bf(float f) {
    __hip_bfloat16 h = __float2bfloat16(f);
    return *(ushort*)&h;
}

// ---------------------------------------------------------------------------
// Fused prep: blocks [0,768) convert X fp32->bf16; blocks [768, 768+2880)
// transpose+convert the 5 weight matrices W[k][n] -> WT[n][k] bf16.
// ---------------------------------------------------------------------------
__global__ __launch_bounds__(256) void prep_k(
    const float* __restrict__ X,
    const float* __restrict__ Wq, const float* __restrict__ Wk,
    const float* __restrict__ Wv, const float* __restrict__ Wo,
    const float* __restrict__ Wd,
    ushort* __restrict__ xb,
    ushort* __restrict__ qT, ushort* __restrict__ kT, ushort* __restrict__ vT,
    ushort* __restrict__ oT, ushort* __restrict__ dT)
{
    __shared__ float t[32][33];
    int bx = blockIdx.x;
    if (bx < 768) {                                  // X conversion
        int i = bx * 256 + threadIdx.x;              // float4 index
        float4 f = ((const float4*)X)[i];
        ushort4 u;
        u.x = f2bf(f.x); u.y = f2bf(f.y); u.z = f2bf(f.z); u.w = f2bf(f.w);
        ((ushort4*)xb)[i] = u;
        return;
    }
    int bz = bx - 768;                               // 0..2879
    int z = bz / 576;
    int rem = bz % 576;
    int k0 = (rem / 24) * 32, n0 = (rem % 24) * 32;
    const float* W; ushort* O;
    if (z == 0)      { W = Wq; O = qT; }
    else if (z == 1) { W = Wk; O = kT; }
    else if (z == 2) { W = Wv; O = vT; }
    else if (z == 3) { W = Wo; O = oT; }
    else             { W = Wd; O = dT; }
    int tx = threadIdx.x & 31, ty = threadIdx.x >> 5;   // ty 0..7
    #pragma unroll
    for (int i = 0; i < 4; i++)
        t[ty + i * 8][tx] = W[(k0 + ty + i * 8) * DD + n0 + tx];
    __syncthreads();
    #pragma unroll
    for (int i = 0; i < 4; i++)
        O[(n0 + ty + i * 8) * DD + k0 + tx] = f2bf(t[tx][ty + i * 8]);
}

// ---------------------------------------------------------------------------
// QKV MFMA GEMM: xb[1024][768] @ W^T -> q,k [H][T][64], v as vT [H][64][T].
// Grid (16, 12, 3); 4 waves, each 32x32 of a 64x64 tile. No LDS.
// ---------------------------------------------------------------------------
__global__ __launch_bounds__(256) void qkv_mfma_k(
    const ushort* __restrict__ xb,
    const ushort* __restrict__ wqT, const ushort* __restrict__ wkT,
    const ushort* __restrict__ wvT,
    const float* __restrict__ bq, const float* __restrict__ bk,
    const float* __restrict__ bv,
    ushort* __restrict__ qo, ushort* __restrict__ ko, ushort* __restrict__ vTo)
{
    int z = blockIdx.z;
    const ushort* BT = (z == 0) ? wqT : (z == 1) ? wkT : wvT;
    const float* bias = (z == 0) ? bq : (z == 1) ? bk : bv;

    int lane = threadIdx.x & 63, w = threadIdx.x >> 6;
    int lr = lane & 15, lg = lane >> 4;
    int row0 = blockIdx.x * 64 + (w >> 1) * 32;
    int h = blockIdx.y;
    int col0 = h * 64 + (w & 1) * 32;

    f32x4 acc00 = {0,0,0,0}, acc01 = {0,0,0,0}, acc10 = {0,0,0,0}, acc11 = {0,0,0,0};
    const ushort* a0p = xb + (size_t)(row0 + lr) * DD + lg * 8;
    const ushort* a1p = a0p + 16 * DD;
    const ushort* b0p = BT + (size_t)(col0 + lr) * DD + lg * 8;
    const ushort* b1p = b0p + 16 * DD;
    #pragma unroll 4
    for (int k0 = 0; k0 < DD; k0 += 32) {
        bfrag a0 = ldg8(a0p + k0), a1 = ldg8(a1p + k0);
        bfrag b0 = ldg8(b0p + k0), b1 = ldg8(b1p + k0);
        acc00 = MFMA(a0, b0, acc00); acc01 = MFMA(a0, b1, acc01);
        acc10 = MFMA(a1, b0, acc10); acc11 = MFMA(a1, b1, acc11);
    }
    #pragma unroll
    for (int mt = 0; mt < 2; mt++) {
        #pragma unroll
        for (int nt = 0; nt < 2; nt++) {
            f32x4 acc = (mt == 0) ? (nt == 0 ? acc00 : acc01)
                                  : (nt == 0 ? acc10 : acc11);
            #pragma unroll
            for (int j = 0; j < 4; j++) {
                int r = row0 + mt * 16 + lg * 4 + j;
                int c = col0 + nt * 16 + lr;            // global col
                ushort u = f2bf(acc[j] + bias[c]);
                int cc = c - h * 64;                    // col within head
                if (z == 2)      vTo[(size_t)(h * 64 + cc) * TT + r] = u;
                else if (z == 0) qo[(size_t)(h * TT + r) * 64 + cc] = u;
                else             ko[(size_t)(h * TT + r) * 64 + cc] = u;
            }
        }
    }
}

// ---------------------------------------------------------------------------
// Generic MFMA GEMM: A[1024][768] bf16 @ BT (pre-transposed) + bias.
// OUTF32=0 -> bf16 out, OUTF32=1 -> f32 out. Grid (16,12).
// ---------------------------------------------------------------------------
template <int OUTF32>
__global__ __launch_bounds__(256) void mm_mfma_k(
    const ushort* __restrict__ A, const ushort* __restrict__ BT,
    const float* __restrict__ bias, void* __restrict__ out)
{
    int lane = threadIdx.x & 63, w = threadIdx.x >> 6;
    int lr = lane & 15, lg = lane >> 4;
    int row0 = blockIdx.x * 64 + (w >> 1) * 32;
    int col0 = blockIdx.y * 64 + (w & 1) * 32;

    f32x4 acc00 = {0,0,0,0}, acc01 = {0,0,0,0}, acc10 = {0,0,0,0}, acc11 = {0,0,0,0};
    const ushort* a0p = A + (size_t)(row0 + lr) * DD + lg * 8;
    const ushort* a1p = a0p + 16 * DD;
    const ushort* b0p = BT + (size_t)(col0 + lr) * DD + lg * 8;
    const ushort* b1p = b0p + 16 * DD;
    #pragma unroll 4
    for (int k0 = 0; k0 < DD; k0 += 32) {
        bfrag a0 = ldg8(a0p + k0), a1 = ldg8(a1p + k0);
        bfrag b0 = ldg8(b0p + k0), b1 = ldg8(b1p + k0);
        acc00 = MFMA(a0, b0, acc00); acc01 = MFMA(a0, b1, acc01);
        acc10 = MFMA(a1, b0, acc10); acc11 = MFMA(a1, b1, acc11);
    }
    #pragma unroll
    for (int mt = 0; mt < 2; mt++) {
        #pragma unroll
        for (int nt = 0; nt < 2; nt++) {
            f32x4 acc = (mt == 0) ? (nt == 0 ? acc00 : acc01)
                                  : (nt == 0 ? acc10 : acc11);
            #pragma unroll
            for (int j = 0; j < 4; j++) {
                int r = row0 + mt * 16 + lg * 4 + j;
                int c = col0 + nt * 16 + lr;
                float v = acc[j] + bias[c];
                if (OUTF32) ((float*)out)[(size_t)r * DD + c] = v;
                else        ((ushort*)out)[(size_t)r * DD + c] = f2bf(v);
            }
        }
    }
}

// ---------------------------------------------------------------------------
// Attention wave core: 16 q-rows vs 8 key blocks (512 keys), ACCUMULATES
// into o[] / lsum[] (no-max softmax partials merge by plain add).
// S = Q K^T via MFMA -> scale/mask/exp -> P (bf16, swizzled per-wave LDS)
// -> O += P V via MFMA. Row-sum reduce happens in the caller.
// ---------------------------------------------------------------------------
__device__ __forceinline__ void attn_core(
    const ushort* __restrict__ kbf, const ushort* __restrict__ vT,
    const int* __restrict__ mask, const int kblk[8], int h,
    bfrag aq0, bfrag aq1, ushort* __restrict__ Pw,
    f32x4 (&o)[4], float (&lsum)[4])
{
    int lane = threadIdx.x & 63, lr = lane & 15, lg = lane >> 4;
    #pragma unroll
    for (int kb = 0; kb < 8; kb++) {
        int bi = kblk[kb];
        #pragma unroll
        for (int kt = 0; kt < 4; kt++) {
            int key = bi * 64 + kt * 16 + lr;
            const ushort* krow = kbf + (size_t)(h * TT + key) * 64 + lg * 8;
            bfrag b0 = ldg8(krow);
            bfrag b1 = ldg8(krow + 32);
            f32x4 s = {0, 0, 0, 0};
            s = MFMA(aq0, b0, s);
            s = MFMA(aq1, b1, s);
            int mk = mask[key];
            #pragma unroll
            for (int j = 0; j < 4; j++) {
                float pv = (mk > 0) ? __expf(s[j] * 0.125f) : 0.0f;
                lsum[j] += pv;
                int row = lg * 4 + j;
                int idx = (row * 512 + (kb * 4 + kt) * 16 + lr) ^ ((row & 7) << 3);
                Pw[idx] = f2bf(pv);
            }
        }
    }
    #pragma unroll
    for (int ks = 0; ks < 16; ks++) {          // 32-key chunks of gathered axis
        int bi = kblk[ks >> 1];
        int pidx = (lr * 512 + ks * 32 + lg * 8) ^ ((lr & 7) << 3);
        bfrag pa = *(const bfrag*)(Pw + pidx);
        #pragma unroll
        for (int dt = 0; dt < 4; dt++) {
            const ushort* vrow = vT + (size_t)(h * 64 + dt * 16 + lr) * TT
                               + bi * 64 + (ks & 1) * 32 + lg * 8;
            o[dt] = MFMA(pa, ldg8(vrow), o[dt]);
        }
    }
}

// ---------------------------------------------------------------------------
// Unified attention: grid (16, 12). x<14 -> mid block n=x (8 gathered key
// blocks). x=14,15 -> global q-blocks 0 / 15: run the core twice over key
// blocks 0-7 then 8-15, accumulating. Writes normalized ctx (bf16) directly.
// ---------------------------------------------------------------------------
__global__ __launch_bounds__(256) void attn_k(
    const ushort* __restrict__ qbf, const ushort* __restrict__ kbf,
    const ushort* __restrict__ vT, const int* __restrict__ mask,
    const int* __restrict__ rnd, ushort* __restrict__ ctx)
{
    __shared__ ushort P[4][16 * 512];
    int x = blockIdx.x, h = blockIdx.y, w = threadIdx.x >> 6;
    int lane = threadIdx.x & 63, lr = lane & 15, lg = lane >> 4;

    int qb = (x < NMID) ? (x + 1) : ((x == NMID) ? 0 : (NBLK - 1));
    int qtok0 = qb * 64 + w * 16;
    const ushort* qrow = qbf + (size_t)(h * TT + qtok0 + lr) * 64 + lg * 8;
    bfrag aq0 = ldg8(qrow);
    bfrag aq1 = ldg8(qrow + 32);

    f32x4 zero = {0, 0, 0, 0};
    f32x4 o[4] = {zero, zero, zero, zero};
    float l[4] = {0.f, 0.f, 0.f, 0.f};

    if (x < NMID) {
        int n = x;
        int kblk[8] = { 0, NBLK - 1, n, n + 1, n + 2,
                        rnd[n * 3 + 0], rnd[n * 3 + 1], rnd[n * 3 + 2] };
        attn_core(kbf, vT, mask, kblk, h, aq0, aq1, &P[w][0], o, l);
    } else {
        int kblk[8];
        #pragma unroll
        for (int kb = 0; kb < 8; kb++) kblk[kb] = kb;
        attn_core(kbf, vT, mask, kblk, h, aq0, aq1, &P[w][0], o, l);
        #pragma unroll
        for (int kb = 0; kb < 8; kb++) kblk[kb] = 8 + kb;
        attn_core(kbf, vT, mask, kblk, h, aq0, aq1, &P[w][0], o, l);
    }

    float inv[4];
    #pragma unroll
    for (int j = 0; j < 4; j++) {
        float s = l[j];
        s += __shfl_xor(s, 1); s += __shfl_xor(s, 2);
        s += __shfl_xor(s, 4); s += __shfl_xor(s, 8);
        inv[j] = 1.0f / s;
    }
    #pragma unroll
    for (int dt = 0; dt < 4; dt++)
        #pragma unroll
        for (int j = 0; j < 4; j++)
            ctx[(size_t)(qtok0 + lg * 4 + j) * DD + h * 64 + dt * 16 + lr] =
                f2bf(o[dt][j] * inv[j]);
}

// ---------------------------------------------------------------------------
// Fused LayerNorm + final projection. One block per token:
// LN(hs row) -> LDS -> out[t,0:16] = hsn @ Wc + bc.
// ---------------------------------------------------------------------------
__global__ __launch_bounds__(256) void ln_out_k(
    const float* __restrict__ hs, const float* __restrict__ g,
    const float* __restrict__ b, const float* __restrict__ Wc,
    const float* __restrict__ bc, float* __restrict__ out)
{
    int t = blockIdx.x;
    int tid = threadIdx.x;
    __shared__ float red[256];
    __shared__ float hsn[768];

    float x0 = hs[t * DD + tid];
    float x1 = hs[t * DD + tid + 256];
    float x2 = hs[t * DD + tid + 512];

    red[tid] = x0 + x1 + x2;
    __syncthreads();
    for (int off = 128; off > 0; off >>= 1) {
        if (tid < off) red[tid] += red[tid + off];
        __syncthreads();
    }
    float mean = red[0] * (1.0f / 768.0f);
    __syncthreads();

    float d0 = x0 - mean, d1 = x1 - mean, d2 = x2 - mean;
    red[tid] = d0 * d0 + d1 * d1 + d2 * d2;
    __syncthreads();
    for (int off = 128; off > 0; off >>= 1) {
        if (tid < off) red[tid] += red[tid + off];
        __syncthreads();
    }
    float var = red[0] * (1.0f / 768.0f);
    float rstd = rsqrtf(var + 1e-12f);

    hsn[tid]       = d0 * rstd * g[tid]       + b[tid];
    hsn[tid + 256] = d1 * rstd * g[tid + 256] + b[tid + 256];
    hsn[tid + 512] = d2 * rstd * g[tid + 512] + b[tid + 512];
    __syncthreads();

    // out projection: 16 cols x 16 threads/col
    int c = tid >> 4, i = tid & 15;
    float s = 0.0f;
    #pragma unroll 8
    for (int j = 0; j < 48; j++) {
        int kk = i * 48 + j;
        s += hsn[kk] * Wc[kk * NCOUT + c];
    }
    s += __shfl_xor(s, 1); s += __shfl_xor(s, 2);
    s += __shfl_xor(s, 4); s += __shfl_xor(s, 8);
    if (i == 0) out[t * NCOUT + c] = s + bc[c];
}

// ---------------------------------------------------------------------------
extern "C" void kernel_launch(void* const* d_in, const int* in_sizes, int n_in,
                              void* d_out, int out_size, void* d_ws, size_t ws_size,
                              hipStream_t stream)
{
    const float* hidden = (const float*)d_in[0];
    const int*   mask   = (const int*)d_in[1];
    const int*   rnd    = (const int*)d_in[2];
    const float* Wq = (const float*)d_in[3];
    const float* bq = (const float*)d_in[4];
    const float* Wk = (const float*)d_in[5];
    const float* bk = (const float*)d_in[6];
    const float* Wv = (const float*)d_in[7];
    const float* bv = (const float*)d_in[8];
    const float* Wo = (const float*)d_in[9];
    const float* bo = (const float*)d_in[10];
    const float* Wd = (const float*)d_in[11];
    const float* bd = (const float*)d_in[12];
    const float* lng = (const float*)d_in[13];
    const float* lnb = (const float*)d_in[14];
    const float* Wc = (const float*)d_in[15];
    const float* bc = (const float*)d_in[16];
    float* out = (float*)d_out;

    // Only the LAST layer's hidden state reaches the output (out = hs[-1]).
    int L = in_sizes[0] / (TT * DD);
    const float* X = hidden + (size_t)(L - 1) * TT * DD;

    const size_t TD  = (size_t)TT * DD;     // 786432
    const size_t WSZ = (size_t)DD * DD;     // 589824

    ushort* xb   = (ushort*)d_ws;
    ushort* wqT  = xb   + TD;
    ushort* wkT  = wqT  + WSZ;
    ushort* wvT  = wkT  + WSZ;
    ushort* woT  = wvT  + WSZ;
    ushort* wdT  = woT  + WSZ;
    ushort* qbf  = wdT  + WSZ;
    ushort* kbf  = qbf  + TD;
    ushort* vTb  = kbf  + TD;
    ushort* ctxb = vTb  + TD;
    ushort* attb = ctxb + TD;
    float*  hs   = (float*)(attb + TD);

    prep_k<<<768 + 2880, 256, 0, stream>>>(X, Wq, Wk, Wv, Wo, Wd,
                                           xb, wqT, wkT, wvT, woT, wdT);
    qkv_mfma_k<<<dim3(16, NHEAD, 3), 256, 0, stream>>>(xb, wqT, wkT, wvT,
                                                       bq, bk, bv, qbf, kbf, vTb);
    attn_k<<<dim3(16, NHEAD), 256, 0, stream>>>(qbf, kbf, vTb, mask, rnd, ctxb);
    mm_mfma_k<0><<<dim3(16, NHEAD), 256, 0, stream>>>(ctxb, woT, bo, attb);
    mm_mfma_k<1><<<dim3(16, NHEAD), 256, 0, stream>>>(attb, wdT, bd, hs);
    ln_out_k<<<TT, 256, 0, stream>>>(hs, lng, lnb, Wc, bc, out);
}

// Round 5
// 127.208 us; speedup vs baseline: 9.3815x; 1.0654x over previous
//
#include <hip/hip_runtime.h>
#include <hip/hip_bf16.h>
#include <math.h>

#define TT    1024   // B*S tokens
#define DD    768    // hidden dim
#define NHEAD 12
#define HDIM  64
#define NBLK  16
#define NMID  14
#define NCOUT 16

typedef __attribute__((ext_vector_type(4))) float f32x4;
typedef __attribute__((ext_vector_type(8))) short bfrag;   // 8 bf16 = 4 VGPRs

#define MFMA(a, b, c) __builtin_amdgcn_mfma_f32_16x16x32_bf16(a, b, c, 0, 0, 0)

__device__ __forceinline__ bfrag ldg8(const ushort* p) { return *(const bfrag*)p; }
__device__ __forceinline__ ushort f2bf(float f) {
    __hip_bfloat16 h = __float2bfloat16(f);
    return *(ushort*)&h;
}

// ---------------------------------------------------------------------------
// Fused prep: blocks [0,768) convert X fp32->bf16; blocks [768, 768+2880)
// transpose+convert the 5 weight matrices W[k][n] -> WT[n][k] bf16.
// ---------------------------------------------------------------------------
__global__ __launch_bounds__(256) void prep_k(
    const float* __restrict__ X,
    const float* __restrict__ Wq, const float* __restrict__ Wk,
    const float* __restrict__ Wv, const float* __restrict__ Wo,
    const float* __restrict__ Wd,
    ushort* __restrict__ xb,
    ushort* __restrict__ qT, ushort* __restrict__ kT, ushort* __restrict__ vT,
    ushort* __restrict__ oT, ushort* __restrict__ dT)
{
    __shared__ float t[32][33];
    int bx = blockIdx.x;
    if (bx < 768) {                                  // X conversion
        int i = bx * 256 + threadIdx.x;              // float4 index
        float4 f = ((const float4*)X)[i];
        ushort4 u;
        u.x = f2bf(f.x); u.y = f2bf(f.y); u.z = f2bf(f.z); u.w = f2bf(f.w);
        ((ushort4*)xb)[i] = u;
        return;
    }
    int bz = bx - 768;                               // 0..2879
    int z = bz / 576;
    int rem = bz % 576;
    int k0 = (rem / 24) * 32, n0 = (rem % 24) * 32;
    const float* W; ushort* O;
    if (z == 0)      { W = Wq; O = qT; }
    else if (z == 1) { W = Wk; O = kT; }
    else if (z == 2) { W = Wv; O = vT; }
    else if (z == 3) { W = Wo; O = oT; }
    else             { W = Wd; O = dT; }
    int tx = threadIdx.x & 31, ty = threadIdx.x >> 5;   // ty 0..7
    #pragma unroll
    for (int i = 0; i < 4; i++)
        t[ty + i * 8][tx] = W[(k0 + ty + i * 8) * DD + n0 + tx];
    __syncthreads();
    #pragma unroll
    for (int i = 0; i < 4; i++)
        O[(n0 + ty + i * 8) * DD + k0 + tx] = f2bf(t[tx][ty + i * 8]);
}

// ---------------------------------------------------------------------------
// QKV MFMA GEMM: xb[1024][768] @ W^T -> q,k [H][T][64], v as vT [H][64][T].
// Grid (16, 12, 3); 4 waves, each 32x32 of a 64x64 tile. No LDS.
// ---------------------------------------------------------------------------
__global__ __launch_bounds__(256) void qkv_mfma_k(
    const ushort* __restrict__ xb,
    const ushort* __restrict__ wqT, const ushort* __restrict__ wkT,
    const ushort* __restrict__ wvT,
    const float* __restrict__ bq, const float* __restrict__ bk,
    const float* __restrict__ bv,
    ushort* __restrict__ qo, ushort* __restrict__ ko, ushort* __restrict__ vTo)
{
    int z = blockIdx.z;
    const ushort* BT = (z == 0) ? wqT : (z == 1) ? wkT : wvT;
    const float* bias = (z == 0) ? bq : (z == 1) ? bk : bv;

    int lane = threadIdx.x & 63, w = threadIdx.x >> 6;
    int lr = lane & 15, lg = lane >> 4;
    int row0 = blockIdx.x * 64 + (w >> 1) * 32;
    int h = blockIdx.y;
    int col0 = h * 64 + (w & 1) * 32;

    f32x4 acc00 = {0,0,0,0}, acc01 = {0,0,0,0}, acc10 = {0,0,0,0}, acc11 = {0,0,0,0};
    const ushort* a0p = xb + (size_t)(row0 + lr) * DD + lg * 8;
    const ushort* a1p = a0p + 16 * DD;
    const ushort* b0p = BT + (size_t)(col0 + lr) * DD + lg * 8;
    const ushort* b1p = b0p + 16 * DD;
    #pragma unroll 4
    for (int k0 = 0; k0 < DD; k0 += 32) {
        bfrag a0 = ldg8(a0p + k0), a1 = ldg8(a1p + k0);
        bfrag b0 = ldg8(b0p + k0), b1 = ldg8(b1p + k0);
        acc00 = MFMA(a0, b0, acc00); acc01 = MFMA(a0, b1, acc01);
        acc10 = MFMA(a1, b0, acc10); acc11 = MFMA(a1, b1, acc11);
    }
    #pragma unroll
    for (int mt = 0; mt < 2; mt++) {
        #pragma unroll
        for (int nt = 0; nt < 2; nt++) {
            f32x4 acc = (mt == 0) ? (nt == 0 ? acc00 : acc01)
                                  : (nt == 0 ? acc10 : acc11);
            #pragma unroll
            for (int j = 0; j < 4; j++) {
                int r = row0 + mt * 16 + lg * 4 + j;
                int c = col0 + nt * 16 + lr;            // global col
                ushort u = f2bf(acc[j] + bias[c]);
                int cc = c - h * 64;                    // col within head
                if (z == 2)      vTo[(size_t)(h * 64 + cc) * TT + r] = u;
                else if (z == 0) qo[(size_t)(h * TT + r) * 64 + cc] = u;
                else             ko[(size_t)(h * TT + r) * 64 + cc] = u;
            }
        }
    }
}

// ---------------------------------------------------------------------------
// Generic MFMA GEMM: A[1024][768] bf16 @ BT (pre-transposed) + bias.
// OUTF32=0 -> bf16 out, OUTF32=1 -> f32 out. Grid (16,12).
// ---------------------------------------------------------------------------
template <int OUTF32>
__global__ __launch_bounds__(256) void mm_mfma_k(
    const ushort* __restrict__ A, const ushort* __restrict__ BT,
    const float* __restrict__ bias, void* __restrict__ out)
{
    int lane = threadIdx.x & 63, w = threadIdx.x >> 6;
    int lr = lane & 15, lg = lane >> 4;
    int row0 = blockIdx.x * 64 + (w >> 1) * 32;
    int col0 = blockIdx.y * 64 + (w & 1) * 32;

    f32x4 acc00 = {0,0,0,0}, acc01 = {0,0,0,0}, acc10 = {0,0,0,0}, acc11 = {0,0,0,0};
    const ushort* a0p = A + (size_t)(row0 + lr) * DD + lg * 8;
    const ushort* a1p = a0p + 16 * DD;
    const ushort* b0p = BT + (size_t)(col0 + lr) * DD + lg * 8;
    const ushort* b1p = b0p + 16 * DD;
    #pragma unroll 4
    for (int k0 = 0; k0 < DD; k0 += 32) {
        bfrag a0 = ldg8(a0p + k0), a1 = ldg8(a1p + k0);
        bfrag b0 = ldg8(b0p + k0), b1 = ldg8(b1p + k0);
        acc00 = MFMA(a0, b0, acc00); acc01 = MFMA(a0, b1, acc01);
        acc10 = MFMA(a1, b0, acc10); acc11 = MFMA(a1, b1, acc11);
    }
    #pragma unroll
    for (int mt = 0; mt < 2; mt++) {
        #pragma unroll
        for (int nt = 0; nt < 2; nt++) {
            f32x4 acc = (mt == 0) ? (nt == 0 ? acc00 : acc01)
                                  : (nt == 0 ? acc10 : acc11);
            #pragma unroll
            for (int j = 0; j < 4; j++) {
                int r = row0 + mt * 16 + lg * 4 + j;
                int c = col0 + nt * 16 + lr;
                float v = acc[j] + bias[c];
                if (OUTF32) ((float*)out)[(size_t)r * DD + c] = v;
                else        ((ushort*)out)[(size_t)r * DD + c] = f2bf(v);
            }
        }
    }
}

// ---------------------------------------------------------------------------
// Attention wave core (k-split): 16 q-rows vs NKB key blocks.
// S = Q K^T via MFMA -> scale/mask/exp -> P (bf16, swizzled per-wave LDS)
// -> O += P V via MFMA. Partial o/lsum merge by plain add (no-max softmax).
// ---------------------------------------------------------------------------
template <int NKB>
__device__ __forceinline__ void attn_core(
    const ushort* __restrict__ kbf, const ushort* __restrict__ vT,
    const int* __restrict__ mask, const int kblk[NKB], int h,
    bfrag aq0, bfrag aq1, ushort* __restrict__ Pw,
    f32x4 (&o)[4], float (&lsum)[4])
{
    int lane = threadIdx.x & 63, lr = lane & 15, lg = lane >> 4;
    #pragma unroll
    for (int kb = 0; kb < NKB; kb++) {
        int bi = kblk[kb];
        #pragma unroll
        for (int kt = 0; kt < 4; kt++) {
            int key = bi * 64 + kt * 16 + lr;
            const ushort* krow = kbf + (size_t)(h * TT + key) * 64 + lg * 8;
            bfrag b0 = ldg8(krow);
            bfrag b1 = ldg8(krow + 32);
            f32x4 s = {0, 0, 0, 0};
            s = MFMA(aq0, b0, s);
            s = MFMA(aq1, b1, s);
            int mk = mask[key];
            #pragma unroll
            for (int j = 0; j < 4; j++) {
                float pv = (mk > 0) ? __expf(s[j] * 0.125f) : 0.0f;
                lsum[j] += pv;
                int row = lg * 4 + j;
                int idx = (row * (NKB * 64) + (kb * 4 + kt) * 16 + lr)
                          ^ ((row & 7) << 3);
                Pw[idx] = f2bf(pv);
            }
        }
    }
    #pragma unroll
    for (int ks = 0; ks < NKB * 2; ks++) {     // 32-key chunks
        int bi = kblk[ks >> 1];
        int pidx = (lr * (NKB * 64) + ks * 32 + lg * 8) ^ ((lr & 7) << 3);
        bfrag pa = *(const bfrag*)(Pw + pidx);
        #pragma unroll
        for (int dt = 0; dt < 4; dt++) {
            const ushort* vrow = vT + (size_t)(h * 64 + dt * 16 + lr) * TT
                               + bi * 64 + (ks & 1) * 32 + lg * 8;
            o[dt] = MFMA(pa, ldg8(vrow), o[dt]);
        }
    }
}

// ---------------------------------------------------------------------------
// Attention, k-split across waves. Grid (64, 12): x = 16-row q-tile, y = head.
// qb = x>>2. Mid (qb 1..14): wave w covers 2 of the 8 gathered key blocks.
// Glob (qb 0,15): wave w covers key blocks 4w..4w+3. Cross-wave merge via
// LDS add (valid because no-max softmax partials are plain sums), then wave w
// normalizes and writes output columns w*16..w*16+15.
// ---------------------------------------------------------------------------
__global__ __launch_bounds__(256) void attn_k(
    const ushort* __restrict__ qbf, const ushort* __restrict__ kbf,
    const ushort* __restrict__ vT, const int* __restrict__ mask,
    const int* __restrict__ rnd, ushort* __restrict__ ctx)
{
    __shared__ ushort P[4][16 * 256];
    __shared__ float mo[4][4][4][64];   // [wave][dt][j][lane], conflict-free
    __shared__ float ml[4][16];
    int x = blockIdx.x, h = blockIdx.y;
    int w = threadIdx.x >> 6, lane = threadIdx.x & 63;
    int lr = lane & 15, lg = lane >> 4;

    int qtok0 = x * 16;
    int qb = x >> 2;
    const ushort* qrow = qbf + (size_t)(h * TT + qtok0 + lr) * 64 + lg * 8;
    bfrag aq0 = ldg8(qrow);
    bfrag aq1 = ldg8(qrow + 32);

    f32x4 zero = {0, 0, 0, 0};
    f32x4 o[4] = {zero, zero, zero, zero};
    float l[4] = {0.f, 0.f, 0.f, 0.f};

    if (qb >= 1 && qb <= NMID) {
        int n = qb - 1;
        int b0, b1;
        if (w == 0)      { b0 = 0;              b1 = NBLK - 1;       }
        else if (w == 1) { b0 = n;              b1 = n + 1;          }
        else if (w == 2) { b0 = n + 2;          b1 = rnd[n * 3 + 0]; }
        else             { b0 = rnd[n * 3 + 1]; b1 = rnd[n * 3 + 2]; }
        int kblk[2] = { b0, b1 };
        attn_core<2>(kbf, vT, mask, kblk, h, aq0, aq1, &P[w][0], o, l);
    } else {
        int kblk[4] = { w * 4, w * 4 + 1, w * 4 + 2, w * 4 + 3 };
        attn_core<4>(kbf, vT, mask, kblk, h, aq0, aq1, &P[w][0], o, l);
    }

    // wave-local row-sum reduce (over lr bits), then stage partials in LDS
    #pragma unroll
    for (int j = 0; j < 4; j++) {
        float s = l[j];
        s += __shfl_xor(s, 1); s += __shfl_xor(s, 2);
        s += __shfl_xor(s, 4); s += __shfl_xor(s, 8);
        l[j] = s;
    }
    #pragma unroll
    for (int dt = 0; dt < 4; dt++)
        #pragma unroll
        for (int j = 0; j < 4; j++)
            mo[w][dt][j][lane] = o[dt][j];
    if (lr == 0) {
        #pragma unroll
        for (int j = 0; j < 4; j++) ml[w][lg * 4 + j] = l[j];
    }
    __syncthreads();

    // wave w merges + writes output columns w*16 .. w*16+15
    float lt[4];
    #pragma unroll
    for (int j = 0; j < 4; j++)
        lt[j] = 1.0f / (ml[0][lg * 4 + j] + ml[1][lg * 4 + j] +
                        ml[2][lg * 4 + j] + ml[3][lg * 4 + j]);
    #pragma unroll
    for (int j = 0; j < 4; j++) {
        float of = mo[0][w][j][lane] + mo[1][w][j][lane] +
                   mo[2][w][j][lane] + mo[3][w][j][lane];
        ctx[(size_t)(qtok0 + lg * 4 + j) * DD + h * 64 + w * 16 + lr] =
            f2bf(of * lt[j]);
    }
}

// ---------------------------------------------------------------------------
// Fused LayerNorm + final projection. One block per token:
// LN(hs row) -> LDS -> out[t,0:16] = hsn @ Wc + bc.
// ---------------------------------------------------------------------------
__global__ __launch_bounds__(256) void ln_out_k(
    const float* __restrict__ hs, const float* __restrict__ g,
    const float* __restrict__ b, const float* __restrict__ Wc,
    const float* __restrict__ bc, float* __restrict__ out)
{
    int t = blockIdx.x;
    int tid = threadIdx.x;
    __shared__ float red[256];
    __shared__ float hsn[768];

    float x0 = hs[t * DD + tid];
    float x1 = hs[t * DD + tid + 256];
    float x2 = hs[t * DD + tid + 512];

    red[tid] = x0 + x1 + x2;
    __syncthreads();
    for (int off = 128; off > 0; off >>= 1) {
        if (tid < off) red[tid] += red[tid + off];
        __syncthreads();
    }
    float mean = red[0] * (1.0f / 768.0f);
    __syncthreads();

    float d0 = x0 - mean, d1 = x1 - mean, d2 = x2 - mean;
    red[tid] = d0 * d0 + d1 * d1 + d2 * d2;
    __syncthreads();
    for (int off = 128; off > 0; off >>= 1) {
        if (tid < off) red[tid] += red[tid + off];
        __syncthreads();
    }
    float var = red[0] * (1.0f / 768.0f);
    float rstd = rsqrtf(var + 1e-12f);

    hsn[tid]       = d0 * rstd * g[tid]       + b[tid];
    hsn[tid + 256] = d1 * rstd * g[tid + 256] + b[tid + 256];
    hsn[tid + 512] = d2 * rstd * g[tid + 512] + b[tid + 512];
    __syncthreads();

    // out projection: 16 cols x 16 threads/col
    int c = tid >> 4, i = tid & 15;
    float s = 0.0f;
    #pragma unroll 8
    for (int j = 0; j < 48; j++) {
        int kk = i * 48 + j;
        s += hsn[kk] * Wc[kk * NCOUT + c];
    }
    s += __shfl_xor(s, 1); s += __shfl_xor(s, 2);
    s += __shfl_xor(s, 4); s += __shfl_xor(s, 8);
    if (i == 0) out[t * NCOUT + c] = s + bc[c];
}

// ---------------------------------------------------------------------------
extern "C" void kernel_launch(void* const* d_in, const int* in_sizes, int n_in,
                              void* d_out, int out_size, void* d_ws, size_t ws_size,
                              hipStream_t stream)
{
    const float* hidden = (const float*)d_in[0];
    const int*   mask   = (const int*)d_in[1];
    const int*   rnd    = (const int*)d_in[2];
    const float* Wq = (const float*)d_in[3];
    const float* bq = (const float*)d_in[4];
    const float* Wk = (const float*)d_in[5];
    const float* bk = (const float*)d_in[6];
    const float* Wv = (const float*)d_in[7];
    const float* bv = (const float*)d_in[8];
    const float* Wo = (const float*)d_in[9];
    const float* bo = (const float*)d_in[10];
    const float* Wd = (const float*)d_in[11];
    const float* bd = (const float*)d_in[12];
    const float* lng = (const float*)d_in[13];
    const float* lnb = (const float*)d_in[14];
    const float* Wc = (const float*)d_in[15];
    const float* bc = (const float*)d_in[16];
    float* out = (float*)d_out;

    // Only the LAST layer's hidden state reaches the output (out = hs[-1]).
    int L = in_sizes[0] / (TT * DD);
    const float* X = hidden + (size_t)(L - 1) * TT * DD;

    const size_t TD  = (size_t)TT * DD;     // 786432
    const size_t WSZ = (size_t)DD * DD;     // 589824

    ushort* xb   = (ushort*)d_ws;
    ushort* wqT  = xb   + TD;
    ushort* wkT  = wqT  + WSZ;
    ushort* wvT  = wkT  + WSZ;
    ushort* woT  = wvT  + WSZ;
    ushort* wdT  = woT  + WSZ;
    ushort* qbf  = wdT  + WSZ;
    ushort* kbf  = qbf  + TD;
    ushort* vTb  = kbf  + TD;
    ushort* ctxb = vTb  + TD;
    ushort* attb = ctxb + TD;
    float*  hs   = (float*)(attb + TD);

    prep_k<<<768 + 2880, 256, 0, stream>>>(X, Wq, Wk, Wv, Wo, Wd,
                                           xb, wqT, wkT, wvT, woT, wdT);
    qkv_mfma_k<<<dim3(16, NHEAD, 3), 256, 0, stream>>>(xb, wqT, wkT, wvT,
                                                       bq, bk, bv, qbf, kbf, vTb);
    attn_k<<<dim3(64, NHEAD), 256, 0, stream>>>(qbf, kbf, vTb, mask, rnd, ctxb);
    mm_mfma_k<0><<<dim3(16, NHEAD), 256, 0, stream>>>(ctxb, woT, bo, attb);
    mm_mfma_k<1><<<dim3(16, NHEAD), 256, 0, stream>>>(attb, wdT, bd, hs);
    ln_out_k<<<TT, 256, 0, stream>>>(hs, lng, lnb, Wc, bc, out);
}